// Round 3
// baseline (656.969 us; speedup 1.0000x reference)
//
#include <hip/hip_runtime.h>
#include <cmath>

#define G_ 128
#define N0_ 512
#define H_ 256
#define E_ 524288
#define NODES0 (G_*N0_)

typedef float f2 __attribute__((ext_vector_type(2)));

__device__ __forceinline__ float4 f4fma(float4 a, float s, float4 acc) {
  acc.x = fmaf(a.x, s, acc.x); acc.y = fmaf(a.y, s, acc.y);
  acc.z = fmaf(a.z, s, acc.z); acc.w = fmaf(a.w, s, acc.w);
  return acc;
}

// ---------------- block reduce helper (blockDim.x == 256) ----------------
__device__ __forceinline__ float block_reduce_sum(float v, volatile float* red) {
  #pragma unroll
  for (int off = 32; off > 0; off >>= 1) v += __shfl_down(v, off);
  int lane = threadIdx.x & 63, wid = threadIdx.x >> 6;
  __syncthreads();
  if (lane == 0) red[wid] = v;
  __syncthreads();
  return red[0] + red[1] + red[2] + red[3];
}

// ---------------- p-vector inverse norms ----------------
__global__ __launch_bounds__(256) void pnorm_kernel(const float* __restrict__ p0,
                                                    const float* __restrict__ p1,
                                                    const float* __restrict__ p2,
                                                    float* __restrict__ pinv) {
  __shared__ float red[4];
  const float* p = (blockIdx.x == 0) ? p0 : (blockIdx.x == 1 ? p1 : p2);
  float v = p[threadIdx.x];
  float s = block_reduce_sum(v * v, red);
  if (threadIdx.x == 0) pinv[blockIdx.x] = 1.0f / sqrtf(s);
}

__global__ void init_cum_kernel(int* __restrict__ cum, int n) {
  int v = blockIdx.x * 256 + threadIdx.x;
  if (v < n) cum[v] = v;
}

// ---------------- f32 GEMM: C[M,256] = A[M,256] @ W[256,256] ----------------
// 128x128 tile, 8x8 micro-tile (f2-packed), BK=32, 256 threads.
// A staged transposed [k][m] with XOR swizzle (conflict-free writes+reads),
// register prefetch of next K-tile, packed-f32 FMA candidates.
__device__ __forceinline__ int aswz(int k) { return ((k >> 2) & 7) << 2; }

__global__ __launch_bounds__(256) void gemm_f32_kernel(const float* __restrict__ A,
                                                       const float* __restrict__ W,
                                                       float* __restrict__ C) {
  __shared__ float As[32 * 128];   // [k][m ^ aswz(k)]
  __shared__ float Bs[32 * 132];   // [k][n], stride 132
  const int tid = threadIdx.x;
  const int tx = tid & 15;
  const int ty = tid >> 4;
  const int bm = blockIdx.x >> 1;
  const int bn = blockIdx.x & 1;

  f2 acc[8][4];
  #pragma unroll
  for (int i = 0; i < 8; ++i)
    #pragma unroll
    for (int j = 0; j < 4; ++j) acc[i][j] = (f2){0.0f, 0.0f};

  float4 pa[4], pb[4];
  #pragma unroll
  for (int i = 0; i < 4; ++i) {
    int f = tid + 256 * i;
    int row = f >> 3, c4 = (f & 7) << 2;
    pa[i] = *(const float4*)&A[(size_t)(bm * 128 + row) * 256 + c4];
    int br = f >> 5, bc = (f & 31) << 2;
    pb[i] = *(const float4*)&W[(size_t)br * 256 + bn * 128 + bc];
  }

  for (int k0 = 0; k0 < 256; k0 += 32) {
    // stage prefetched tile into LDS
    #pragma unroll
    for (int i = 0; i < 4; ++i) {
      int f = tid + 256 * i;
      int row = f >> 3, c4 = (f & 7) << 2;
      float vals[4] = {pa[i].x, pa[i].y, pa[i].z, pa[i].w};
      #pragma unroll
      for (int j = 0; j < 4; ++j) {
        int k = c4 + j;
        As[k * 128 + (row ^ aswz(k))] = vals[j];
      }
      int br = f >> 5, bc = (f & 31) << 2;
      *(float4*)&Bs[br * 132 + bc] = pb[i];
    }
    __syncthreads();

    // issue next tile's global loads (overlap with compute)
    if (k0 + 32 < 256) {
      int kn = k0 + 32;
      #pragma unroll
      for (int i = 0; i < 4; ++i) {
        int f = tid + 256 * i;
        int row = f >> 3, c4 = (f & 7) << 2;
        pa[i] = *(const float4*)&A[(size_t)(bm * 128 + row) * 256 + kn + c4];
        int br = f >> 5, bc = (f & 31) << 2;
        pb[i] = *(const float4*)&W[(size_t)(kn + br) * 256 + bn * 128 + bc];
      }
    }

    #pragma unroll 8
    for (int kk = 0; kk < 32; ++kk) {
      const float* arow = &As[kk * 128];
      int sb = aswz(kk);
      float4 a0 = *(const float4*)&arow[(ty * 8) ^ sb];
      float4 a1 = *(const float4*)&arow[(ty * 8 + 4) ^ sb];
      float4 b0 = *(const float4*)&Bs[kk * 132 + tx * 4];
      float4 b1 = *(const float4*)&Bs[kk * 132 + 64 + tx * 4];
      float a[8] = {a0.x, a0.y, a0.z, a0.w, a1.x, a1.y, a1.z, a1.w};
      f2 b[4] = {{b0.x, b0.y}, {b0.z, b0.w}, {b1.x, b1.y}, {b1.z, b1.w}};
      #pragma unroll
      for (int i = 0; i < 8; ++i) {
        f2 av = {a[i], a[i]};
        #pragma unroll
        for (int j = 0; j < 4; ++j)
          acc[i][j] = av * b[j] + acc[i][j];
      }
    }
    __syncthreads();
  }

  #pragma unroll
  for (int i = 0; i < 8; ++i) {
    int row = bm * 128 + ty * 8 + i;
    float4 v0 = make_float4(acc[i][0].x, acc[i][0].y, acc[i][1].x, acc[i][1].y);
    float4 v1 = make_float4(acc[i][2].x, acc[i][2].y, acc[i][3].x, acc[i][3].y);
    *(float4*)&C[(size_t)row * 256 + bn * 128 + tx * 4] = v0;
    *(float4*)&C[(size_t)row * 256 + bn * 128 + 64 + tx * 4] = v1;
  }
}

// ---------------- degree count (valid edges only) ----------------
__global__ void count_deg_kernel(const int* __restrict__ esrc, const int* __restrict__ edst,
                                 const int* __restrict__ cum, int* __restrict__ cnt) {
  int e = blockIdx.x * 256 + threadIdx.x;
  if (e >= E_) return;
  int ms = cum[esrc[e]], md = cum[edst[e]];
  if (ms >= 0 && md >= 0) atomicAdd(&cnt[md], 1);
}

// ---------------- hierarchical exclusive scan over cnt -> row_start ----------------
__global__ __launch_bounds__(256) void scan1_kernel(const int* __restrict__ cnt,
                                                    int* __restrict__ row_start,
                                                    int* __restrict__ bsum,
                                                    float* __restrict__ dis, int n) {
  __shared__ int sdata[256];
  int base = blockIdx.x * 1024;
  int t = threadIdx.x;
  int v[4]; int s = 0;
  #pragma unroll
  for (int i = 0; i < 4; ++i) {
    int idx = base + t * 4 + i;
    v[i] = (idx < n) ? cnt[idx] : 0;
    s += v[i];
    if (idx < n) dis[idx] = 1.0f / sqrtf((float)v[i] + 1.0f);
  }
  sdata[t] = s;
  __syncthreads();
  for (int off = 1; off < 256; off <<= 1) {
    int x = (t >= off) ? sdata[t - off] : 0;
    __syncthreads();
    sdata[t] += x;
    __syncthreads();
  }
  int excl = sdata[t] - s;
  if (t == 255) bsum[blockIdx.x] = sdata[255];
  #pragma unroll
  for (int i = 0; i < 4; ++i) {
    int idx = base + t * 4 + i;
    if (idx < n) { row_start[idx] = excl; excl += v[i]; }
  }
}

__global__ __launch_bounds__(256) void scan2_kernel(int* __restrict__ bsum,
                                                    int* __restrict__ row_start, int nb, int n) {
  __shared__ int sdata[256];
  int t = threadIdx.x;
  int v = (t < nb) ? bsum[t] : 0;
  sdata[t] = v;
  __syncthreads();
  for (int off = 1; off < 256; off <<= 1) {
    int x = (t >= off) ? sdata[t - off] : 0;
    __syncthreads();
    sdata[t] += x;
    __syncthreads();
  }
  if (t < nb) bsum[t] = sdata[t] - v;
  if (t == 255) row_start[n] = sdata[255];
}

__global__ void scan3_kernel(int* __restrict__ row_start, const int* __restrict__ bsum, int n) {
  int idx = blockIdx.x * 256 + threadIdx.x;
  if (idx < n) row_start[idx] += bsum[idx >> 10];
}

// ---------------- CSR fill ----------------
__global__ void fill_csr_kernel(const int* __restrict__ esrc, const int* __restrict__ edst,
                                const int* __restrict__ cum, const int* __restrict__ row_start,
                                int* __restrict__ cursor, const float* __restrict__ dis,
                                int* __restrict__ csr_src, float* __restrict__ csr_cf) {
  int e = blockIdx.x * 256 + threadIdx.x;
  if (e >= E_) return;
  int ms = cum[esrc[e]], md = cum[edst[e]];
  if (ms < 0 || md < 0) return;
  int pos = atomicAdd(&cursor[md], 1);
  int j = row_start[md] + pos;
  csr_src[j] = ms;
  csr_cf[j] = dis[ms] * dis[md];
}

// ---------------- aggregate + bias + relu, fused tanh-score ----------------
__global__ __launch_bounds__(256) void agg_score_kernel(
    const float4* __restrict__ hlin4, const float* __restrict__ dis,
    const float4* __restrict__ bias4,
    const int* __restrict__ row_start, const int* __restrict__ csr_src,
    const float* __restrict__ csr_cf, const float4* __restrict__ p4,
    const float* __restrict__ pinvp,
    float4* __restrict__ hout4, float* __restrict__ score, int q) {
  int blk = (blockIdx.x & 7) * q + (blockIdx.x >> 3);
  int wave = threadIdx.x >> 6, lane = threadIdx.x & 63;
  int v = blk * 4 + wave;
  float dv = dis[v];
  float self = dv * dv;
  float4 h = hlin4[(size_t)v * 64 + lane];
  float4 acc = make_float4(h.x * self, h.y * self, h.z * self, h.w * self);
  int rs = row_start[v], re = row_start[v + 1];
  int j = rs;
  for (; j + 4 <= re; j += 4) {
    int s0 = csr_src[j + 0], s1 = csr_src[j + 1];
    int s2 = csr_src[j + 2], s3 = csr_src[j + 3];
    float c0 = csr_cf[j + 0], c1 = csr_cf[j + 1];
    float c2 = csr_cf[j + 2], c3 = csr_cf[j + 3];
    float4 h0 = hlin4[(size_t)s0 * 64 + lane];
    float4 h1 = hlin4[(size_t)s1 * 64 + lane];
    float4 h2 = hlin4[(size_t)s2 * 64 + lane];
    float4 h3 = hlin4[(size_t)s3 * 64 + lane];
    acc = f4fma(h0, c0, acc); acc = f4fma(h1, c1, acc);
    acc = f4fma(h2, c2, acc); acc = f4fma(h3, c3, acc);
  }
  for (; j < re; ++j) {
    acc = f4fma(hlin4[(size_t)csr_src[j] * 64 + lane], csr_cf[j], acc);
  }
  float4 b = bias4[lane];
  acc.x = fmaxf(acc.x + b.x, 0.0f); acc.y = fmaxf(acc.y + b.y, 0.0f);
  acc.z = fmaxf(acc.z + b.z, 0.0f); acc.w = fmaxf(acc.w + b.w, 0.0f);
  hout4[(size_t)v * 64 + lane] = acc;
  float4 pv = p4[lane];
  float s = acc.x * pv.x + acc.y * pv.y + acc.z * pv.z + acc.w * pv.w;
  #pragma unroll
  for (int off = 32; off > 0; off >>= 1) s += __shfl_down(s, off);
  if (lane == 0) score[v] = tanhf(s * pinvp[0]);
}

// ---------------- per-graph top-k via in-LDS bitonic sort (512 elems) ----------------
__global__ __launch_bounds__(256) void topk_kernel(const float* __restrict__ score, int n, int k,
                                                   int* __restrict__ cur_map, int* __restrict__ perm) {
  __shared__ float key[512];
  __shared__ int kid[512];
  int g = blockIdx.x, t = threadIdx.x;
  for (int i = t; i < 512; i += 256) {
    key[i] = (i < n) ? score[(size_t)g * n + i] : -INFINITY;
    kid[i] = i;
  }
  for (int i = t; i < n; i += 256) cur_map[g * n + i] = -1;
  __syncthreads();
  for (int kk = 2; kk <= 512; kk <<= 1) {
    for (int j = kk >> 1; j > 0; j >>= 1) {
      #pragma unroll
      for (int half = 0; half < 2; ++half) {
        int i = t + half * 256;
        int ixj = i ^ j;
        if (ixj > i) {
          float ka = key[i]; int ia = kid[i];
          float kb = key[ixj]; int ib = kid[ixj];
          bool b_first = (kb > ka) || (kb == ka && ib < ia);
          bool sw = ((i & kk) == 0) ? b_first : !b_first;
          if (sw) { key[i] = kb; kid[i] = ib; key[ixj] = ka; kid[ixj] = ia; }
        }
      }
      __syncthreads();
    }
  }
  for (int i = t; i < k; i += 256) {
    int local = kid[i];
    perm[g * k + i] = g * n + local;
    cur_map[g * n + local] = g * k + i;
  }
}

__global__ void update_cum_kernel(int* __restrict__ cum, const int* __restrict__ cur_map, int n0) {
  int v = blockIdx.x * 256 + threadIdx.x;
  if (v < n0) {
    int c = cum[v];
    if (c >= 0) cum[v] = cur_map[c];
  }
}

// ---------------- gather x_new = h[perm]*score[perm], fused attention gate ----------------
__global__ __launch_bounds__(256) void gather_gate_kernel(
    const float4* __restrict__ h4, const float* __restrict__ score, const int* __restrict__ perm,
    const float4* __restrict__ attw4, const float* __restrict__ attb,
    float4* __restrict__ xnew4, float* __restrict__ gate, int q) {
  int blk = (blockIdx.x & 7) * q + (blockIdx.x >> 3);
  int wave = threadIdx.x >> 6, lane = threadIdx.x & 63;
  int i = blk * 4 + wave;
  int s = perm[i];
  float sc = score[s];
  float4 h = h4[(size_t)s * 64 + lane];
  float4 val = make_float4(h.x * sc, h.y * sc, h.z * sc, h.w * sc);
  xnew4[(size_t)i * 64 + lane] = val;
  float4 aw = attw4[lane];
  float g = val.x * aw.x + val.y * aw.y + val.z * aw.z + val.w * aw.w;
  #pragma unroll
  for (int off = 32; off > 0; off >>= 1) g += __shfl_down(g, off);
  if (lane == 0) gate[i] = g + attb[0];
}

// ---------------- per-graph attention pooling (8 waves split k rows, float4) ----------------
__global__ __launch_bounds__(512) void att_pool_kernel(const float4* __restrict__ x4,
                                                       const float* __restrict__ gate,
                                                       float* __restrict__ out, int k, int add) {
  __shared__ float att[512];
  __shared__ float red[8];
  __shared__ float4 part[512];
  int g = blockIdx.x, t = threadIdx.x;
  int wave = t >> 6, lane = t & 63;
  const float* gg = gate + (size_t)g * k;

  float m = -INFINITY;
  for (int i = t; i < k; i += 512) m = fmaxf(m, gg[i]);
  #pragma unroll
  for (int off = 32; off > 0; off >>= 1) m = fmaxf(m, __shfl_down(m, off));
  if (lane == 0) red[wave] = m;
  __syncthreads();
  m = red[0];
  #pragma unroll
  for (int w = 1; w < 8; ++w) m = fmaxf(m, red[w]);
  __syncthreads();

  float s = 0.0f;
  for (int i = t; i < k; i += 512) {
    float e = expf(gg[i] - m);
    att[i] = e;
    s += e;
  }
  #pragma unroll
  for (int off = 32; off > 0; off >>= 1) s += __shfl_down(s, off);
  if (lane == 0) red[wave] = s;
  __syncthreads();
  s = red[0] + red[1] + red[2] + red[3] + red[4] + red[5] + red[6] + red[7];
  float inv = 1.0f / s;

  float4 acc = make_float4(0.f, 0.f, 0.f, 0.f);
  const float4* xg = x4 + (size_t)g * k * 64;
  for (int i = wave; i < k; i += 8) acc = f4fma(xg[(size_t)i * 64 + lane], att[i], acc);
  part[t] = acc;
  __syncthreads();
  if (wave == 0) {
    float4 r = part[lane];
    #pragma unroll
    for (int w = 1; w < 8; ++w) {
      float4 pw = part[w * 64 + lane];
      r.x += pw.x; r.y += pw.y; r.z += pw.z; r.w += pw.w;
    }
    r.x *= inv; r.y *= inv; r.z *= inv; r.w *= inv;
    float4* o4 = (float4*)out + (size_t)g * 64 + lane;
    if (add) {
      float4 prev = *o4;
      r.x += prev.x; r.y += prev.y; r.z += prev.z; r.w += prev.w;
    }
    *o4 = r;
  }
}

// ---------------- host orchestration ----------------
extern "C" void kernel_launch(void* const* d_in, const int* in_sizes, int n_in,
                              void* d_out, int out_size, void* d_ws, size_t ws_size,
                              hipStream_t stream) {
  const float* x    = (const float*)d_in[0];
  const int*   esrc = (const int*)d_in[1];
  const int*   edst = (const int*)d_in[2];
  const float* Wl[3] = {(const float*)d_in[3], (const float*)d_in[5], (const float*)d_in[7]};
  const float* bl[3] = {(const float*)d_in[4], (const float*)d_in[6], (const float*)d_in[8]};
  const float* pl[3] = {(const float*)d_in[9], (const float*)d_in[10], (const float*)d_in[11]};
  const float* attw = (const float*)d_in[12];
  const float* attb = (const float*)d_in[13];
  float* out = (float*)d_out;

  char* w = (char*)d_ws;
  auto carve = [&](size_t bytes) { char* p = w; w += (bytes + 255) & ~(size_t)255; return p; };
  float* bufA    = (float*)carve((size_t)NODES0 * H_ * 4);
  float* bufB    = (float*)carve((size_t)NODES0 * H_ * 4);
  int*   csr_src = (int*)  carve((size_t)E_ * 4);
  float* csr_cf  = (float*)carve((size_t)E_ * 4);
  int*   cnt     = (int*)  carve((size_t)NODES0 * 4);
  int*   row_st  = (int*)  carve((size_t)(NODES0 + 1) * 4);
  int*   cursor  = (int*)  carve((size_t)NODES0 * 4);
  float* dis     = (float*)carve((size_t)NODES0 * 4);
  float* score   = (float*)carve((size_t)NODES0 * 4);
  int*   cur_map = (int*)  carve((size_t)NODES0 * 4);
  int*   cum_map = (int*)  carve((size_t)NODES0 * 4);
  int*   perm    = (int*)  carve((size_t)NODES0 * 4);
  float* gate    = (float*)carve((size_t)NODES0 * 4);
  int*   bsum    = (int*)  carve(256 * 4);
  float* pinv    = (float*)carve(16);
  (void)ws_size; (void)in_sizes; (void)n_in; (void)out_size;

  pnorm_kernel<<<3, 256, 0, stream>>>(pl[0], pl[1], pl[2], pinv);
  init_cum_kernel<<<NODES0 / 256, 256, 0, stream>>>(cum_map, NODES0);

  int n_cur = N0_;
  const float* xin = x;
  for (int l = 0; l < 3; ++l) {
    int nodes = G_ * n_cur;
    float* hlin = (l & 1) ? bufB : bufA;
    float* hbuf = (l & 1) ? bufA : bufB;
    float* xnew = hlin;

    gemm_f32_kernel<<<(nodes / 128) * 2, 256, 0, stream>>>(xin, Wl[l], hlin);

    hipMemsetAsync(cnt, 0, (size_t)nodes * 4, stream);
    count_deg_kernel<<<E_ / 256, 256, 0, stream>>>(esrc, edst, cum_map, cnt);
    int nb = (nodes + 1023) / 1024;
    scan1_kernel<<<nb, 256, 0, stream>>>(cnt, row_st, bsum, dis, nodes);
    scan2_kernel<<<1, 256, 0, stream>>>(bsum, row_st, nb, nodes);
    scan3_kernel<<<(nodes + 255) / 256, 256, 0, stream>>>(row_st, bsum, nodes);
    hipMemsetAsync(cursor, 0, (size_t)nodes * 4, stream);
    fill_csr_kernel<<<E_ / 256, 256, 0, stream>>>(esrc, edst, cum_map, row_st, cursor, dis,
                                                  csr_src, csr_cf);

    int agg_blocks = nodes / 4;
    agg_score_kernel<<<agg_blocks, 256, 0, stream>>>(
        (const float4*)hlin, dis, (const float4*)bl[l], row_st, csr_src, csr_cf,
        (const float4*)pl[l], pinv + l, (float4*)hbuf, score, agg_blocks / 8);

    int kk = (int)std::ceil(0.8 * (double)n_cur);
    topk_kernel<<<G_, 256, 0, stream>>>(score, n_cur, kk, cur_map, perm);
    update_cum_kernel<<<NODES0 / 256, 256, 0, stream>>>(cum_map, cur_map, NODES0);
    int rows = G_ * kk;
    int gg_blocks = rows / 4;
    gather_gate_kernel<<<gg_blocks, 256, 0, stream>>>(
        (const float4*)hbuf, score, perm, (const float4*)attw, attb,
        (float4*)xnew, gate, gg_blocks / 8);

    att_pool_kernel<<<G_, 512, 0, stream>>>((const float4*)xnew, gate, out, kk, l > 0 ? 1 : 0);

    n_cur = kk;
    xin = xnew;
  }
}

// Round 4
// 495.094 us; speedup vs baseline: 1.3270x; 1.3270x over previous
//
#include <hip/hip_runtime.h>
#include <cmath>

#define G_ 128
#define N0_ 512
#define H_ 256
#define E_ 524288
#define NODES0 (G_*N0_)

typedef _Float16 v8h __attribute__((ext_vector_type(8)));
typedef float v4f __attribute__((ext_vector_type(4)));

__device__ __forceinline__ float4 f4fma(float4 a, float s, float4 acc) {
  acc.x = fmaf(a.x, s, acc.x); acc.y = fmaf(a.y, s, acc.y);
  acc.z = fmaf(a.z, s, acc.z); acc.w = fmaf(a.w, s, acc.w);
  return acc;
}

// ---------------- block reduce helper (blockDim.x == 256) ----------------
__device__ __forceinline__ float block_reduce_sum(float v, volatile float* red) {
  #pragma unroll
  for (int off = 32; off > 0; off >>= 1) v += __shfl_down(v, off);
  int lane = threadIdx.x & 63, wid = threadIdx.x >> 6;
  __syncthreads();
  if (lane == 0) red[wid] = v;
  __syncthreads();
  return red[0] + red[1] + red[2] + red[3];
}

// ---------------- p-vector inverse norms ----------------
__global__ __launch_bounds__(256) void pnorm_kernel(const float* __restrict__ p0,
                                                    const float* __restrict__ p1,
                                                    const float* __restrict__ p2,
                                                    float* __restrict__ pinv) {
  __shared__ float red[4];
  const float* p = (blockIdx.x == 0) ? p0 : (blockIdx.x == 1 ? p1 : p2);
  float v = p[threadIdx.x];
  float s = block_reduce_sum(v * v, red);
  if (threadIdx.x == 0) pinv[blockIdx.x] = 1.0f / sqrtf(s);
}

__global__ void init_cum_kernel(int* __restrict__ cum, int n) {
  int v = blockIdx.x * 256 + threadIdx.x;
  if (v < n) cum[v] = v;
}

// ---------------- W -> f16 hi/lo transposed LDS-image ----------------
// Image: per (bn in 0..1, kt in 0..7): 128 rows (n_local), each 80 halfwords:
//   [0..31]  = hi of W[kt*32 + j][bn*128 + n]   (j = 0..31)
//   [32..63] = lo
//   [64..79] = pad
__global__ __launch_bounds__(256) void wconv_kernel(const float* __restrict__ W,
                                                    _Float16* __restrict__ img) {
  int bn = blockIdx.x >> 3, kt = blockIdx.x & 7;
  int t = threadIdx.x;
  int n = t & 127, kh = t >> 7;        // kh = 0/1 -> k 0..15 / 16..31
  int k0 = kt * 32 + kh * 16;
  _Float16* row = img + ((size_t)(bn * 8 + kt) * 128 + n) * 80;
  #pragma unroll
  for (int s = 0; s < 2; ++s) {        // two groups of 8 k's
    v8h hv, lv;
    #pragma unroll
    for (int j = 0; j < 8; ++j) {
      float a = W[(size_t)(k0 + s * 8 + j) * 256 + bn * 128 + n];
      _Float16 h = (_Float16)a;
      hv[j] = h;
      lv[j] = (_Float16)(a - (float)h);
    }
    *(v8h*)&row[kh * 16 + s * 8] = hv;
    *(v8h*)&row[32 + kh * 16 + s * 8] = lv;
  }
}

// ---------------- f16x3 MFMA GEMM: C[M,256] = A[M,256] @ W[256,256] ----------------
// 128x128 block tile, 4 waves (2x2), each wave 64x64 = 4x4 fragments of 16x16.
// BK=32 (one mfma_f32_16x16x32_f16 per fragment per pass), 3 passes:
// hi*hi + lo*hi + hi*lo  (lo*lo dropped, ~2^-22 relative).
__global__ __launch_bounds__(256) void gemm_f16x3_kernel(const float* __restrict__ A,
                                                         const _Float16* __restrict__ Wimg,
                                                         float* __restrict__ C) {
  __shared__ _Float16 As[128 * 80];
  __shared__ _Float16 Ws[128 * 80];
  const int tid = threadIdx.x;
  const int bm = blockIdx.x >> 1;
  const int bn = blockIdx.x & 1;
  const int lane = tid & 63, wid = tid >> 6;
  const int wm = wid >> 1, wn = wid & 1;
  const int l15 = lane & 15, kg = lane >> 4;

  v4f acc[4][4];
  #pragma unroll
  for (int i = 0; i < 4; ++i)
    #pragma unroll
    for (int j = 0; j < 4; ++j) acc[i][j] = (v4f){0.f, 0.f, 0.f, 0.f};

  const int arow = tid >> 1, ahalf = tid & 1;   // A staging: 2 threads per row
  const float* Ag = A + (size_t)(bm * 128 + arow) * 256 + ahalf * 16;
  _Float16* Arow = &As[arow * 80 + ahalf * 16];

  for (int kt = 0; kt < 8; ++kt) {
    __syncthreads();
    // ---- stage A: load 16 f32, split to f16 hi/lo ----
    #pragma unroll
    for (int s = 0; s < 2; ++s) {
      float4 x = *(const float4*)(Ag + kt * 32 + s * 8);
      float4 y = *(const float4*)(Ag + kt * 32 + s * 8 + 4);
      float av[8] = {x.x, x.y, x.z, x.w, y.x, y.y, y.z, y.w};
      v8h hv, lv;
      #pragma unroll
      for (int j = 0; j < 8; ++j) {
        _Float16 h = (_Float16)av[j];
        hv[j] = h;
        lv[j] = (_Float16)(av[j] - (float)h);
      }
      *(v8h*)&Arow[s * 8] = hv;
      *(v8h*)&Arow[32 + s * 8] = lv;
    }
    // ---- stage B: flat coalesced copy of pre-built image tile (20 KB) ----
    {
      const float4* src = (const float4*)(Wimg + (size_t)(bn * 8 + kt) * 128 * 80);
      float4* dst = (float4*)Ws;
      #pragma unroll
      for (int c = tid; c < 1280; c += 256) dst[c] = src[c];
    }
    __syncthreads();

    // ---- fragments ----
    v8h ah[4], bh[4], al[4], bl[4];
    #pragma unroll
    for (int i = 0; i < 4; ++i)
      ah[i] = *(const v8h*)&As[(wm * 64 + i * 16 + l15) * 80 + kg * 8];
    #pragma unroll
    for (int j = 0; j < 4; ++j)
      bh[j] = *(const v8h*)&Ws[(wn * 64 + j * 16 + l15) * 80 + kg * 8];
    #pragma unroll
    for (int i = 0; i < 4; ++i)
      #pragma unroll
      for (int j = 0; j < 4; ++j)
        acc[i][j] = __builtin_amdgcn_mfma_f32_16x16x32_f16(ah[i], bh[j], acc[i][j], 0, 0, 0);
    #pragma unroll
    for (int i = 0; i < 4; ++i)
      al[i] = *(const v8h*)&As[(wm * 64 + i * 16 + l15) * 80 + 32 + kg * 8];
    #pragma unroll
    for (int i = 0; i < 4; ++i)
      #pragma unroll
      for (int j = 0; j < 4; ++j)
        acc[i][j] = __builtin_amdgcn_mfma_f32_16x16x32_f16(al[i], bh[j], acc[i][j], 0, 0, 0);
    #pragma unroll
    for (int j = 0; j < 4; ++j)
      bl[j] = *(const v8h*)&Ws[(wn * 64 + j * 16 + l15) * 80 + 32 + kg * 8];
    #pragma unroll
    for (int i = 0; i < 4; ++i)
      #pragma unroll
      for (int j = 0; j < 4; ++j)
        acc[i][j] = __builtin_amdgcn_mfma_f32_16x16x32_f16(ah[i], bl[j], acc[i][j], 0, 0, 0);
  }

  // ---- epilogue: C[row][col], row = .. + kg*4 + r, col = .. + l15 ----
  #pragma unroll
  for (int i = 0; i < 4; ++i) {
    #pragma unroll
    for (int j = 0; j < 4; ++j) {
      #pragma unroll
      for (int r = 0; r < 4; ++r) {
        int row = bm * 128 + wm * 64 + i * 16 + kg * 4 + r;
        int col = bn * 128 + wn * 64 + j * 16 + l15;
        C[(size_t)row * 256 + col] = acc[i][j][r];
      }
    }
  }
}

// ---------------- degree count (valid edges only) ----------------
__global__ void count_deg_kernel(const int* __restrict__ esrc, const int* __restrict__ edst,
                                 const int* __restrict__ cum, int* __restrict__ cnt) {
  int e = blockIdx.x * 256 + threadIdx.x;
  if (e >= E_) return;
  int ms = cum[esrc[e]], md = cum[edst[e]];
  if (ms >= 0 && md >= 0) atomicAdd(&cnt[md], 1);
}

// ---------------- hierarchical exclusive scan over cnt -> row_start ----------------
__global__ __launch_bounds__(256) void scan1_kernel(const int* __restrict__ cnt,
                                                    int* __restrict__ row_start,
                                                    int* __restrict__ bsum,
                                                    float* __restrict__ dis, int n) {
  __shared__ int sdata[256];
  int base = blockIdx.x * 1024;
  int t = threadIdx.x;
  int v[4]; int s = 0;
  #pragma unroll
  for (int i = 0; i < 4; ++i) {
    int idx = base + t * 4 + i;
    v[i] = (idx < n) ? cnt[idx] : 0;
    s += v[i];
    if (idx < n) dis[idx] = 1.0f / sqrtf((float)v[i] + 1.0f);
  }
  sdata[t] = s;
  __syncthreads();
  for (int off = 1; off < 256; off <<= 1) {
    int x = (t >= off) ? sdata[t - off] : 0;
    __syncthreads();
    sdata[t] += x;
    __syncthreads();
  }
  int excl = sdata[t] - s;
  if (t == 255) bsum[blockIdx.x] = sdata[255];
  #pragma unroll
  for (int i = 0; i < 4; ++i) {
    int idx = base + t * 4 + i;
    if (idx < n) { row_start[idx] = excl; excl += v[i]; }
  }
}

__global__ __launch_bounds__(256) void scan2_kernel(int* __restrict__ bsum,
                                                    int* __restrict__ row_start, int nb, int n) {
  __shared__ int sdata[256];
  int t = threadIdx.x;
  int v = (t < nb) ? bsum[t] : 0;
  sdata[t] = v;
  __syncthreads();
  for (int off = 1; off < 256; off <<= 1) {
    int x = (t >= off) ? sdata[t - off] : 0;
    __syncthreads();
    sdata[t] += x;
    __syncthreads();
  }
  if (t < nb) bsum[t] = sdata[t] - v;
  if (t == 255) row_start[n] = sdata[255];
}

__global__ void scan3_kernel(int* __restrict__ row_start, const int* __restrict__ bsum, int n) {
  int idx = blockIdx.x * 256 + threadIdx.x;
  if (idx < n) row_start[idx] += bsum[idx >> 10];
}

// ---------------- CSR fill ----------------
__global__ void fill_csr_kernel(const int* __restrict__ esrc, const int* __restrict__ edst,
                                const int* __restrict__ cum, const int* __restrict__ row_start,
                                int* __restrict__ cursor, const float* __restrict__ dis,
                                int* __restrict__ csr_src, float* __restrict__ csr_cf) {
  int e = blockIdx.x * 256 + threadIdx.x;
  if (e >= E_) return;
  int ms = cum[esrc[e]], md = cum[edst[e]];
  if (ms < 0 || md < 0) return;
  int pos = atomicAdd(&cursor[md], 1);
  int j = row_start[md] + pos;
  csr_src[j] = ms;
  csr_cf[j] = dis[ms] * dis[md];
}

// ---------------- aggregate + bias + relu, fused tanh-score ----------------
__global__ __launch_bounds__(256) void agg_score_kernel(
    const float4* __restrict__ hlin4, const float* __restrict__ dis,
    const float4* __restrict__ bias4,
    const int* __restrict__ row_start, const int* __restrict__ csr_src,
    const float* __restrict__ csr_cf, const float4* __restrict__ p4,
    const float* __restrict__ pinvp,
    float4* __restrict__ hout4, float* __restrict__ score, int q) {
  int blk = (blockIdx.x & 7) * q + (blockIdx.x >> 3);
  int wave = threadIdx.x >> 6, lane = threadIdx.x & 63;
  int v = blk * 4 + wave;
  float dv = dis[v];
  float self = dv * dv;
  float4 h = hlin4[(size_t)v * 64 + lane];
  float4 acc = make_float4(h.x * self, h.y * self, h.z * self, h.w * self);
  int rs = row_start[v], re = row_start[v + 1];
  int j = rs;
  for (; j + 4 <= re; j += 4) {
    int s0 = csr_src[j + 0], s1 = csr_src[j + 1];
    int s2 = csr_src[j + 2], s3 = csr_src[j + 3];
    float c0 = csr_cf[j + 0], c1 = csr_cf[j + 1];
    float c2 = csr_cf[j + 2], c3 = csr_cf[j + 3];
    float4 h0 = hlin4[(size_t)s0 * 64 + lane];
    float4 h1 = hlin4[(size_t)s1 * 64 + lane];
    float4 h2 = hlin4[(size_t)s2 * 64 + lane];
    float4 h3 = hlin4[(size_t)s3 * 64 + lane];
    acc = f4fma(h0, c0, acc); acc = f4fma(h1, c1, acc);
    acc = f4fma(h2, c2, acc); acc = f4fma(h3, c3, acc);
  }
  for (; j < re; ++j) {
    acc = f4fma(hlin4[(size_t)csr_src[j] * 64 + lane], csr_cf[j], acc);
  }
  float4 b = bias4[lane];
  acc.x = fmaxf(acc.x + b.x, 0.0f); acc.y = fmaxf(acc.y + b.y, 0.0f);
  acc.z = fmaxf(acc.z + b.z, 0.0f); acc.w = fmaxf(acc.w + b.w, 0.0f);
  hout4[(size_t)v * 64 + lane] = acc;
  float4 pv = p4[lane];
  float s = acc.x * pv.x + acc.y * pv.y + acc.z * pv.z + acc.w * pv.w;
  #pragma unroll
  for (int off = 32; off > 0; off >>= 1) s += __shfl_down(s, off);
  if (lane == 0) score[v] = tanhf(s * pinvp[0]);
}

// ---------------- per-graph top-k via in-LDS bitonic sort (512 elems) ----------------
__global__ __launch_bounds__(256) void topk_kernel(const float* __restrict__ score, int n, int k,
                                                   int* __restrict__ cur_map, int* __restrict__ perm) {
  __shared__ float key[512];
  __shared__ int kid[512];
  int g = blockIdx.x, t = threadIdx.x;
  for (int i = t; i < 512; i += 256) {
    key[i] = (i < n) ? score[(size_t)g * n + i] : -INFINITY;
    kid[i] = i;
  }
  for (int i = t; i < n; i += 256) cur_map[g * n + i] = -1;
  __syncthreads();
  for (int kk = 2; kk <= 512; kk <<= 1) {
    for (int j = kk >> 1; j > 0; j >>= 1) {
      #pragma unroll
      for (int half = 0; half < 2; ++half) {
        int i = t + half * 256;
        int ixj = i ^ j;
        if (ixj > i) {
          float ka = key[i]; int ia = kid[i];
          float kb = key[ixj]; int ib = kid[ixj];
          bool b_first = (kb > ka) || (kb == ka && ib < ia);
          bool sw = ((i & kk) == 0) ? b_first : !b_first;
          if (sw) { key[i] = kb; kid[i] = ib; key[ixj] = ka; kid[ixj] = ia; }
        }
      }
      __syncthreads();
    }
  }
  for (int i = t; i < k; i += 256) {
    int local = kid[i];
    perm[g * k + i] = g * n + local;
    cur_map[g * n + local] = g * k + i;
  }
}

__global__ void update_cum_kernel(int* __restrict__ cum, const int* __restrict__ cur_map, int n0) {
  int v = blockIdx.x * 256 + threadIdx.x;
  if (v < n0) {
    int c = cum[v];
    if (c >= 0) cum[v] = cur_map[c];
  }
}

// ---------------- gather x_new = h[perm]*score[perm], fused attention gate ----------------
__global__ __launch_bounds__(256) void gather_gate_kernel(
    const float4* __restrict__ h4, const float* __restrict__ score, const int* __restrict__ perm,
    const float4* __restrict__ attw4, const float* __restrict__ attb,
    float4* __restrict__ xnew4, float* __restrict__ gate, int q) {
  int blk = (blockIdx.x & 7) * q + (blockIdx.x >> 3);
  int wave = threadIdx.x >> 6, lane = threadIdx.x & 63;
  int i = blk * 4 + wave;
  int s = perm[i];
  float sc = score[s];
  float4 h = h4[(size_t)s * 64 + lane];
  float4 val = make_float4(h.x * sc, h.y * sc, h.z * sc, h.w * sc);
  xnew4[(size_t)i * 64 + lane] = val;
  float4 aw = attw4[lane];
  float g = val.x * aw.x + val.y * aw.y + val.z * aw.z + val.w * aw.w;
  #pragma unroll
  for (int off = 32; off > 0; off >>= 1) g += __shfl_down(g, off);
  if (lane == 0) gate[i] = g + attb[0];
}

// ---------------- per-graph attention pooling (8 waves split k rows, float4) ----------------
__global__ __launch_bounds__(512) void att_pool_kernel(const float4* __restrict__ x4,
                                                       const float* __restrict__ gate,
                                                       float* __restrict__ out, int k, int add) {
  __shared__ float att[512];
  __shared__ float red[8];
  __shared__ float4 part[512];
  int g = blockIdx.x, t = threadIdx.x;
  int wave = t >> 6, lane = t & 63;
  const float* gg = gate + (size_t)g * k;

  float m = -INFINITY;
  for (int i = t; i < k; i += 512) m = fmaxf(m, gg[i]);
  #pragma unroll
  for (int off = 32; off > 0; off >>= 1) m = fmaxf(m, __shfl_down(m, off));
  if (lane == 0) red[wave] = m;
  __syncthreads();
  m = red[0];
  #pragma unroll
  for (int w = 1; w < 8; ++w) m = fmaxf(m, red[w]);
  __syncthreads();

  float s = 0.0f;
  for (int i = t; i < k; i += 512) {
    float e = expf(gg[i] - m);
    att[i] = e;
    s += e;
  }
  #pragma unroll
  for (int off = 32; off > 0; off >>= 1) s += __shfl_down(s, off);
  if (lane == 0) red[wave] = s;
  __syncthreads();
  s = red[0] + red[1] + red[2] + red[3] + red[4] + red[5] + red[6] + red[7];
  float inv = 1.0f / s;

  float4 acc = make_float4(0.f, 0.f, 0.f, 0.f);
  const float4* xg = x4 + (size_t)g * k * 64;
  for (int i = wave; i < k; i += 8) acc = f4fma(xg[(size_t)i * 64 + lane], att[i], acc);
  part[t] = acc;
  __syncthreads();
  if (wave == 0) {
    float4 r = part[lane];
    #pragma unroll
    for (int w = 1; w < 8; ++w) {
      float4 pw = part[w * 64 + lane];
      r.x += pw.x; r.y += pw.y; r.z += pw.z; r.w += pw.w;
    }
    r.x *= inv; r.y *= inv; r.z *= inv; r.w *= inv;
    float4* o4 = (float4*)out + (size_t)g * 64 + lane;
    if (add) {
      float4 prev = *o4;
      r.x += prev.x; r.y += prev.y; r.z += prev.z; r.w += prev.w;
    }
    *o4 = r;
  }
}

// ---------------- host orchestration ----------------
extern "C" void kernel_launch(void* const* d_in, const int* in_sizes, int n_in,
                              void* d_out, int out_size, void* d_ws, size_t ws_size,
                              hipStream_t stream) {
  const float* x    = (const float*)d_in[0];
  const int*   esrc = (const int*)d_in[1];
  const int*   edst = (const int*)d_in[2];
  const float* Wl[3] = {(const float*)d_in[3], (const float*)d_in[5], (const float*)d_in[7]};
  const float* bl[3] = {(const float*)d_in[4], (const float*)d_in[6], (const float*)d_in[8]};
  const float* pl[3] = {(const float*)d_in[9], (const float*)d_in[10], (const float*)d_in[11]};
  const float* attw = (const float*)d_in[12];
  const float* attb = (const float*)d_in[13];
  float* out = (float*)d_out;

  char* w = (char*)d_ws;
  auto carve = [&](size_t bytes) { char* p = w; w += (bytes + 255) & ~(size_t)255; return p; };
  float* bufA    = (float*)carve((size_t)NODES0 * H_ * 4);
  float* bufB    = (float*)carve((size_t)NODES0 * H_ * 4);
  int*   csr_src = (int*)  carve((size_t)E_ * 4);
  float* csr_cf  = (float*)carve((size_t)E_ * 4);
  int*   cnt     = (int*)  carve((size_t)NODES0 * 4);
  int*   row_st  = (int*)  carve((size_t)(NODES0 + 1) * 4);
  int*   cursor  = (int*)  carve((size_t)NODES0 * 4);
  float* dis     = (float*)carve((size_t)NODES0 * 4);
  float* score   = (float*)carve((size_t)NODES0 * 4);
  int*   cur_map = (int*)  carve((size_t)NODES0 * 4);
  int*   cum_map = (int*)  carve((size_t)NODES0 * 4);
  int*   perm    = (int*)  carve((size_t)NODES0 * 4);
  float* gate    = (float*)carve((size_t)NODES0 * 4);
  int*   bsum    = (int*)  carve(256 * 4);
  float* pinv    = (float*)carve(16);
  _Float16* Wimg = (_Float16*)carve((size_t)2 * 8 * 128 * 80 * 2);  // 320 KB
  (void)ws_size; (void)in_sizes; (void)n_in; (void)out_size;

  pnorm_kernel<<<3, 256, 0, stream>>>(pl[0], pl[1], pl[2], pinv);
  init_cum_kernel<<<NODES0 / 256, 256, 0, stream>>>(cum_map, NODES0);

  int n_cur = N0_;
  const float* xin = x;
  for (int l = 0; l < 3; ++l) {
    int nodes = G_ * n_cur;
    float* hlin = (l & 1) ? bufB : bufA;
    float* hbuf = (l & 1) ? bufA : bufB;
    float* xnew = hlin;

    // h_lin = X @ W  via f16x3 MFMA
    wconv_kernel<<<16, 256, 0, stream>>>(Wl[l], Wimg);
    gemm_f16x3_kernel<<<(nodes / 128) * 2, 256, 0, stream>>>(xin, Wimg, hlin);

    hipMemsetAsync(cnt, 0, (size_t)nodes * 4, stream);
    count_deg_kernel<<<E_ / 256, 256, 0, stream>>>(esrc, edst, cum_map, cnt);
    int nb = (nodes + 1023) / 1024;
    scan1_kernel<<<nb, 256, 0, stream>>>(cnt, row_st, bsum, dis, nodes);
    scan2_kernel<<<1, 256, 0, stream>>>(bsum, row_st, nb, nodes);
    scan3_kernel<<<(nodes + 255) / 256, 256, 0, stream>>>(row_st, bsum, nodes);
    hipMemsetAsync(cursor, 0, (size_t)nodes * 4, stream);
    fill_csr_kernel<<<E_ / 256, 256, 0, stream>>>(esrc, edst, cum_map, row_st, cursor, dis,
                                                  csr_src, csr_cf);

    int agg_blocks = nodes / 4;
    agg_score_kernel<<<agg_blocks, 256, 0, stream>>>(
        (const float4*)hlin, dis, (const float4*)bl[l], row_st, csr_src, csr_cf,
        (const float4*)pl[l], pinv + l, (float4*)hbuf, score, agg_blocks / 8);

    int kk = (int)std::ceil(0.8 * (double)n_cur);
    topk_kernel<<<G_, 256, 0, stream>>>(score, n_cur, kk, cur_map, perm);
    update_cum_kernel<<<NODES0 / 256, 256, 0, stream>>>(cum_map, cur_map, NODES0);
    int rows = G_ * kk;
    int gg_blocks = rows / 4;
    gather_gate_kernel<<<gg_blocks, 256, 0, stream>>>(
        (const float4*)hbuf, score, perm, (const float4*)attw, attb,
        (float4*)xnew, gate, gg_blocks / 8);

    att_pool_kernel<<<G_, 512, 0, stream>>>((const float4*)xnew, gate, out, kk, l > 0 ? 1 : 0);

    n_cur = kk;
    xin = xnew;
  }
}

// Round 5
// 447.283 us; speedup vs baseline: 1.4688x; 1.1069x over previous
//
#include <hip/hip_runtime.h>
#include <cmath>

#define G_ 128
#define N0_ 512
#define H_ 256
#define E_ 524288
#define NODES0 (G_*N0_)

typedef _Float16 v8h __attribute__((ext_vector_type(8)));
typedef _Float16 v4h __attribute__((ext_vector_type(4)));
typedef float v4f __attribute__((ext_vector_type(4)));

#define TSTRIDE 72   // halfwords per tile row: 32 hi + 32 lo + 8 pad (36 words = 4 mod 32 -> conflict-free b128 reads)

__device__ __forceinline__ void async_copy16(void* lds, const void* g) {
  __builtin_amdgcn_global_load_lds(
      (const __attribute__((address_space(1))) void*)g,
      (__attribute__((address_space(3))) void*)lds, 16, 0, 0);
}

__device__ __forceinline__ float4 f4fma(float4 a, float s, float4 acc) {
  acc.x = fmaf(a.x, s, acc.x); acc.y = fmaf(a.y, s, acc.y);
  acc.z = fmaf(a.z, s, acc.z); acc.w = fmaf(a.w, s, acc.w);
  return acc;
}

// ---------------- block reduce helper (blockDim.x == 256) ----------------
__device__ __forceinline__ float block_reduce_sum(float v, volatile float* red) {
  #pragma unroll
  for (int off = 32; off > 0; off >>= 1) v += __shfl_down(v, off);
  int lane = threadIdx.x & 63, wid = threadIdx.x >> 6;
  __syncthreads();
  if (lane == 0) red[wid] = v;
  __syncthreads();
  return red[0] + red[1] + red[2] + red[3];
}

// ---------------- p-vector inverse norms ----------------
__global__ __launch_bounds__(256) void pnorm_kernel(const float* __restrict__ p0,
                                                    const float* __restrict__ p1,
                                                    const float* __restrict__ p2,
                                                    float* __restrict__ pinv) {
  __shared__ float red[4];
  const float* p = (blockIdx.x == 0) ? p0 : (blockIdx.x == 1 ? p1 : p2);
  float v = p[threadIdx.x];
  float s = block_reduce_sum(v * v, red);
  if (threadIdx.x == 0) pinv[blockIdx.x] = 1.0f / sqrtf(s);
}

__global__ void init_cum_kernel(int* __restrict__ cum, int n) {
  int v = blockIdx.x * 256 + threadIdx.x;
  if (v < n) cum[v] = v;
}

// ---------------- W -> f16 hi/lo transposed LDS-image ----------------
// Per (bn, kt) tile: 128 rows (n_local), TSTRIDE halfwords each:
//   [0..31]=hi of W[kt*32+j][bn*128+n], [32..63]=lo, [64..71]=pad.
// Byte-exact image of the GEMM's Ws LDS buffer (enables linear global_load_lds).
__global__ __launch_bounds__(256) void wconv_kernel(const float* __restrict__ W,
                                                    _Float16* __restrict__ img) {
  int bn = blockIdx.x >> 3, kt = blockIdx.x & 7;
  int t = threadIdx.x;
  int n = t & 127, kh = t >> 7;        // kh = 0/1 -> k 0..15 / 16..31
  int k0 = kt * 32 + kh * 16;
  _Float16* row = img + ((size_t)(bn * 8 + kt) * 128 + n) * TSTRIDE;
  #pragma unroll
  for (int s = 0; s < 2; ++s) {
    v8h hv, lv;
    #pragma unroll
    for (int j = 0; j < 8; ++j) {
      float a = W[(size_t)(k0 + s * 8 + j) * 256 + bn * 128 + n];
      _Float16 h = (_Float16)a;
      hv[j] = h;
      lv[j] = (_Float16)(a - (float)h);
    }
    *(v8h*)&row[kh * 16 + s * 8] = hv;
    *(v8h*)&row[32 + kh * 16 + s * 8] = lv;
  }
}

// ---------------- f16x3 MFMA GEMM: C[M,256] = A[M,256] @ W[256,256] ----------------
// 128x128 block tile, 4 waves (2x2), wave = 64x64 = 4x4 fragments, BK=32, 8 kt iters.
// hi*hi + lo*hi + hi*lo passes. W staged via global_load_lds from prebuilt image;
// A slice register-prefetched (coalesced 16B chunks), converted hi/lo into LDS.
__global__ __launch_bounds__(256) void gemm_f16x3_kernel(const float* __restrict__ A,
                                                         const _Float16* __restrict__ Wimg,
                                                         float* __restrict__ C) {
  __shared__ _Float16 As[128 * TSTRIDE];
  __shared__ _Float16 Ws[128 * TSTRIDE];
  const int tid = threadIdx.x;
  const int bm = blockIdx.x >> 1;
  const int bn = blockIdx.x & 1;
  const int lane = tid & 63, wid = tid >> 6;
  const int wm = wid >> 1, wn = wid & 1;
  const int l15 = lane & 15, kg = lane >> 4;

  v4f acc[4][4];
  #pragma unroll
  for (int i = 0; i < 4; ++i)
    #pragma unroll
    for (int j = 0; j < 4; ++j) acc[i][j] = (v4f){0.f, 0.f, 0.f, 0.f};

  // A staging map: slice = 128 rows x 32 cols; 1024 16B-chunks; thread owns c = tid + 256*i.
  int arow[4], acc4[4];
  const float* aptr[4];
  #pragma unroll
  for (int i = 0; i < 4; ++i) {
    int c = tid + 256 * i;
    arow[i] = c >> 3;
    acc4[i] = c & 7;
    aptr[i] = A + (size_t)(bm * 128 + arow[i]) * 256 + acc4[i] * 4;
  }
  const _Float16* wtile0 = Wimg + (size_t)bn * 8 * 128 * TSTRIDE;

  float4 pa[4];
  #pragma unroll
  for (int i = 0; i < 4; ++i) pa[i] = *(const float4*)(aptr[i] + 0);

  for (int kt = 0; kt < 8; ++kt) {
    // ---- issue W-tile async copy (18 KB linear, 18 wave-chunks of 1 KB) ----
    {
      const _Float16* wt = wtile0 + (size_t)kt * 128 * TSTRIDE;
      for (int cb = wid; cb < 18; cb += 4)
        async_copy16(&Ws[cb * 512 + 0], wt + (size_t)cb * 512 + lane * 8);
    }
    // ---- convert prefetched A slice -> hi/lo in LDS (overlaps W fetch) ----
    #pragma unroll
    for (int i = 0; i < 4; ++i) {
      float av[4] = {pa[i].x, pa[i].y, pa[i].z, pa[i].w};
      v4h hv, lv;
      #pragma unroll
      for (int j = 0; j < 4; ++j) {
        _Float16 h = (_Float16)av[j];
        hv[j] = h;
        lv[j] = (_Float16)(av[j] - (float)h);
      }
      _Float16* dst = &As[arow[i] * TSTRIDE + acc4[i] * 4];
      *(v4h*)(dst) = hv;
      *(v4h*)(dst + 32) = lv;
    }
    __syncthreads();   // drains W async loads (vmcnt) + A LDS writes (lgkm)

    // ---- prefetch next A slice (flies during MFMA section) ----
    if (kt < 7) {
      #pragma unroll
      for (int i = 0; i < 4; ++i)
        pa[i] = *(const float4*)(aptr[i] + (kt + 1) * 32);
    }

    // ---- fragments + 48 MFMA ----
    v8h ah[4], bh[4], al[4], bl[4];
    #pragma unroll
    for (int i = 0; i < 4; ++i)
      ah[i] = *(const v8h*)&As[(wm * 64 + i * 16 + l15) * TSTRIDE + kg * 8];
    #pragma unroll
    for (int j = 0; j < 4; ++j)
      bh[j] = *(const v8h*)&Ws[(wn * 64 + j * 16 + l15) * TSTRIDE + kg * 8];
    #pragma unroll
    for (int i = 0; i < 4; ++i)
      #pragma unroll
      for (int j = 0; j < 4; ++j)
        acc[i][j] = __builtin_amdgcn_mfma_f32_16x16x32_f16(ah[i], bh[j], acc[i][j], 0, 0, 0);
    #pragma unroll
    for (int i = 0; i < 4; ++i)
      al[i] = *(const v8h*)&As[(wm * 64 + i * 16 + l15) * TSTRIDE + 32 + kg * 8];
    #pragma unroll
    for (int i = 0; i < 4; ++i)
      #pragma unroll
      for (int j = 0; j < 4; ++j)
        acc[i][j] = __builtin_amdgcn_mfma_f32_16x16x32_f16(al[i], bh[j], acc[i][j], 0, 0, 0);
    #pragma unroll
    for (int j = 0; j < 4; ++j)
      bl[j] = *(const v8h*)&Ws[(wn * 64 + j * 16 + l15) * TSTRIDE + 32 + kg * 8];
    #pragma unroll
    for (int i = 0; i < 4; ++i)
      #pragma unroll
      for (int j = 0; j < 4; ++j)
        acc[i][j] = __builtin_amdgcn_mfma_f32_16x16x32_f16(ah[i], bl[j], acc[i][j], 0, 0, 0);
    __syncthreads();
  }

  // ---- epilogue ----
  #pragma unroll
  for (int i = 0; i < 4; ++i) {
    #pragma unroll
    for (int j = 0; j < 4; ++j) {
      #pragma unroll
      for (int r = 0; r < 4; ++r) {
        int row = bm * 128 + wm * 64 + i * 16 + kg * 4 + r;
        int col = bn * 128 + wn * 64 + j * 16 + l15;
        C[(size_t)row * 256 + col] = acc[i][j][r];
      }
    }
  }
}

// ---------------- degree count (valid edges only) ----------------
__global__ void count_deg_kernel(const int* __restrict__ esrc, const int* __restrict__ edst,
                                 const int* __restrict__ cum, int* __restrict__ cnt) {
  int e = blockIdx.x * 256 + threadIdx.x;
  if (e >= E_) return;
  int ms = cum[esrc[e]], md = cum[edst[e]];
  if (ms >= 0 && md >= 0) atomicAdd(&cnt[md], 1);
}

// ---------------- hierarchical exclusive scan over cnt -> row_start ----------------
__global__ __launch_bounds__(256) void scan1_kernel(const int* __restrict__ cnt,
                                                    int* __restrict__ row_start,
                                                    int* __restrict__ bsum,
                                                    float* __restrict__ dis, int n) {
  __shared__ int sdata[256];
  int base = blockIdx.x * 1024;
  int t = threadIdx.x;
  int v[4]; int s = 0;
  #pragma unroll
  for (int i = 0; i < 4; ++i) {
    int idx = base + t * 4 + i;
    v[i] = (idx < n) ? cnt[idx] : 0;
    s += v[i];
    if (idx < n) dis[idx] = 1.0f / sqrtf((float)v[i] + 1.0f);
  }
  sdata[t] = s;
  __syncthreads();
  for (int off = 1; off < 256; off <<= 1) {
    int x = (t >= off) ? sdata[t - off] : 0;
    __syncthreads();
    sdata[t] += x;
    __syncthreads();
  }
  int excl = sdata[t] - s;
  if (t == 255) bsum[blockIdx.x] = sdata[255];
  #pragma unroll
  for (int i = 0; i < 4; ++i) {
    int idx = base + t * 4 + i;
    if (idx < n) { row_start[idx] = excl; excl += v[i]; }
  }
}

__global__ __launch_bounds__(256) void scan2_kernel(int* __restrict__ bsum,
                                                    int* __restrict__ row_start, int nb, int n) {
  __shared__ int sdata[256];
  int t = threadIdx.x;
  int v = (t < nb) ? bsum[t] : 0;
  sdata[t] = v;
  __syncthreads();
  for (int off = 1; off < 256; off <<= 1) {
    int x = (t >= off) ? sdata[t - off] : 0;
    __syncthreads();
    sdata[t] += x;
    __syncthreads();
  }
  if (t < nb) bsum[t] = sdata[t] - v;
  if (t == 255) row_start[n] = sdata[255];
}

__global__ void scan3_kernel(int* __restrict__ row_start, const int* __restrict__ bsum, int n) {
  int idx = blockIdx.x * 256 + threadIdx.x;
  if (idx < n) row_start[idx] += bsum[idx >> 10];
}

// ---------------- CSR fill ----------------
__global__ void fill_csr_kernel(const int* __restrict__ esrc, const int* __restrict__ edst,
                                const int* __restrict__ cum, const int* __restrict__ row_start,
                                int* __restrict__ cursor, const float* __restrict__ dis,
                                int* __restrict__ csr_src, float* __restrict__ csr_cf) {
  int e = blockIdx.x * 256 + threadIdx.x;
  if (e >= E_) return;
  int ms = cum[esrc[e]], md = cum[edst[e]];
  if (ms < 0 || md < 0) return;
  int pos = atomicAdd(&cursor[md], 1);
  int j = row_start[md] + pos;
  csr_src[j] = ms;
  csr_cf[j] = dis[ms] * dis[md];
}

// ---------------- aggregate + bias + relu, fused tanh-score ----------------
__global__ __launch_bounds__(256) void agg_score_kernel(
    const float4* __restrict__ hlin4, const float* __restrict__ dis,
    const float4* __restrict__ bias4,
    const int* __restrict__ row_start, const int* __restrict__ csr_src,
    const float* __restrict__ csr_cf, const float4* __restrict__ p4,
    const float* __restrict__ pinvp,
    float4* __restrict__ hout4, float* __restrict__ score, int q) {
  int blk = (blockIdx.x & 7) * q + (blockIdx.x >> 3);
  int wave = threadIdx.x >> 6, lane = threadIdx.x & 63;
  int v = blk * 4 + wave;
  float dv = dis[v];
  float self = dv * dv;
  float4 h = hlin4[(size_t)v * 64 + lane];
  float4 acc = make_float4(h.x * self, h.y * self, h.z * self, h.w * self);
  int rs = row_start[v], re = row_start[v + 1];
  int j = rs;
  for (; j + 4 <= re; j += 4) {
    int s0 = csr_src[j + 0], s1 = csr_src[j + 1];
    int s2 = csr_src[j + 2], s3 = csr_src[j + 3];
    float c0 = csr_cf[j + 0], c1 = csr_cf[j + 1];
    float c2 = csr_cf[j + 2], c3 = csr_cf[j + 3];
    float4 h0 = hlin4[(size_t)s0 * 64 + lane];
    float4 h1 = hlin4[(size_t)s1 * 64 + lane];
    float4 h2 = hlin4[(size_t)s2 * 64 + lane];
    float4 h3 = hlin4[(size_t)s3 * 64 + lane];
    acc = f4fma(h0, c0, acc); acc = f4fma(h1, c1, acc);
    acc = f4fma(h2, c2, acc); acc = f4fma(h3, c3, acc);
  }
  for (; j < re; ++j) {
    acc = f4fma(hlin4[(size_t)csr_src[j] * 64 + lane], csr_cf[j], acc);
  }
  float4 b = bias4[lane];
  acc.x = fmaxf(acc.x + b.x, 0.0f); acc.y = fmaxf(acc.y + b.y, 0.0f);
  acc.z = fmaxf(acc.z + b.z, 0.0f); acc.w = fmaxf(acc.w + b.w, 0.0f);
  hout4[(size_t)v * 64 + lane] = acc;
  float4 pv = p4[lane];
  float s = acc.x * pv.x + acc.y * pv.y + acc.z * pv.z + acc.w * pv.w;
  #pragma unroll
  for (int off = 32; off > 0; off >>= 1) s += __shfl_down(s, off);
  if (lane == 0) score[v] = tanhf(s * pinvp[0]);
}

// ---------------- per-graph top-k via in-LDS bitonic sort (512 elems) ----------------
__global__ __launch_bounds__(256) void topk_kernel(const float* __restrict__ score, int n, int k,
                                                   int* __restrict__ cur_map, int* __restrict__ perm) {
  __shared__ float key[512];
  __shared__ int kid[512];
  int g = blockIdx.x, t = threadIdx.x;
  for (int i = t; i < 512; i += 256) {
    key[i] = (i < n) ? score[(size_t)g * n + i] : -INFINITY;
    kid[i] = i;
  }
  for (int i = t; i < n; i += 256) cur_map[g * n + i] = -1;
  __syncthreads();
  for (int kk = 2; kk <= 512; kk <<= 1) {
    for (int j = kk >> 1; j > 0; j >>= 1) {
      #pragma unroll
      for (int half = 0; half < 2; ++half) {
        int i = t + half * 256;
        int ixj = i ^ j;
        if (ixj > i) {
          float ka = key[i]; int ia = kid[i];
          float kb = key[ixj]; int ib = kid[ixj];
          bool b_first = (kb > ka) || (kb == ka && ib < ia);
          bool sw = ((i & kk) == 0) ? b_first : !b_first;
          if (sw) { key[i] = kb; kid[i] = ib; key[ixj] = ka; kid[ixj] = ia; }
        }
      }
      __syncthreads();
    }
  }
  for (int i = t; i < k; i += 256) {
    int local = kid[i];
    perm[g * k + i] = g * n + local;
    cur_map[g * n + local] = g * k + i;
  }
}

__global__ void update_cum_kernel(int* __restrict__ cum, const int* __restrict__ cur_map, int n0) {
  int v = blockIdx.x * 256 + threadIdx.x;
  if (v < n0) {
    int c = cum[v];
    if (c >= 0) cum[v] = cur_map[c];
  }
}

// ---------------- gather x_new = h[perm]*score[perm], fused attention gate ----------------
__global__ __launch_bounds__(256) void gather_gate_kernel(
    const float4* __restrict__ h4, const float* __restrict__ score, const int* __restrict__ perm,
    const float4* __restrict__ attw4, const float* __restrict__ attb,
    float4* __restrict__ xnew4, float* __restrict__ gate, int q) {
  int blk = (blockIdx.x & 7) * q + (blockIdx.x >> 3);
  int wave = threadIdx.x >> 6, lane = threadIdx.x & 63;
  int i = blk * 4 + wave;
  int s = perm[i];
  float sc = score[s];
  float4 h = h4[(size_t)s * 64 + lane];
  float4 val = make_float4(h.x * sc, h.y * sc, h.z * sc, h.w * sc);
  xnew4[(size_t)i * 64 + lane] = val;
  float4 aw = attw4[lane];
  float g = val.x * aw.x + val.y * aw.y + val.z * aw.z + val.w * aw.w;
  #pragma unroll
  for (int off = 32; off > 0; off >>= 1) g += __shfl_down(g, off);
  if (lane == 0) gate[i] = g + attb[0];
}

// ---------------- per-graph attention pooling (8 waves split k rows, float4) ----------------
__global__ __launch_bounds__(512) void att_pool_kernel(const float4* __restrict__ x4,
                                                       const float* __restrict__ gate,
                                                       float* __restrict__ out, int k, int add) {
  __shared__ float att[512];
  __shared__ float red[8];
  __shared__ float4 part[512];
  int g = blockIdx.x, t = threadIdx.x;
  int wave = t >> 6, lane = t & 63;
  const float* gg = gate + (size_t)g * k;

  float m = -INFINITY;
  for (int i = t; i < k; i += 512) m = fmaxf(m, gg[i]);
  #pragma unroll
  for (int off = 32; off > 0; off >>= 1) m = fmaxf(m, __shfl_down(m, off));
  if (lane == 0) red[wave] = m;
  __syncthreads();
  m = red[0];
  #pragma unroll
  for (int w = 1; w < 8; ++w) m = fmaxf(m, red[w]);
  __syncthreads();

  float s = 0.0f;
  for (int i = t; i < k; i += 512) {
    float e = expf(gg[i] - m);
    att[i] = e;
    s += e;
  }
  #pragma unroll
  for (int off = 32; off > 0; off >>= 1) s += __shfl_down(s, off);
  if (lane == 0) red[wave] = s;
  __syncthreads();
  s = red[0] + red[1] + red[2] + red[3] + red[4] + red[5] + red[6] + red[7];
  float inv = 1.0f / s;

  float4 acc = make_float4(0.f, 0.f, 0.f, 0.f);
  const float4* xg = x4 + (size_t)g * k * 64;
  for (int i = wave; i < k; i += 8) acc = f4fma(xg[(size_t)i * 64 + lane], att[i], acc);
  part[t] = acc;
  __syncthreads();
  if (wave == 0) {
    float4 r = part[lane];
    #pragma unroll
    for (int w = 1; w < 8; ++w) {
      float4 pw = part[w * 64 + lane];
      r.x += pw.x; r.y += pw.y; r.z += pw.z; r.w += pw.w;
    }
    r.x *= inv; r.y *= inv; r.z *= inv; r.w *= inv;
    float4* o4 = (float4*)out + (size_t)g * 64 + lane;
    if (add) {
      float4 prev = *o4;
      r.x += prev.x; r.y += prev.y; r.z += prev.z; r.w += prev.w;
    }
    *o4 = r;
  }
}

// ---------------- host orchestration ----------------
extern "C" void kernel_launch(void* const* d_in, const int* in_sizes, int n_in,
                              void* d_out, int out_size, void* d_ws, size_t ws_size,
                              hipStream_t stream) {
  const float* x    = (const float*)d_in[0];
  const int*   esrc = (const int*)d_in[1];
  const int*   edst = (const int*)d_in[2];
  const float* Wl[3] = {(const float*)d_in[3], (const float*)d_in[5], (const float*)d_in[7]};
  const float* bl[3] = {(const float*)d_in[4], (const float*)d_in[6], (const float*)d_in[8]};
  const float* pl[3] = {(const float*)d_in[9], (const float*)d_in[10], (const float*)d_in[11]};
  const float* attw = (const float*)d_in[12];
  const float* attb = (const float*)d_in[13];
  float* out = (float*)d_out;

  char* w = (char*)d_ws;
  auto carve = [&](size_t bytes) { char* p = w; w += (bytes + 255) & ~(size_t)255; return p; };
  float* bufA    = (float*)carve((size_t)NODES0 * H_ * 4);
  float* bufB    = (float*)carve((size_t)NODES0 * H_ * 4);
  int*   csr_src = (int*)  carve((size_t)E_ * 4);
  float* csr_cf  = (float*)carve((size_t)E_ * 4);
  int*   cnt     = (int*)  carve((size_t)NODES0 * 4);
  int*   row_st  = (int*)  carve((size_t)(NODES0 + 1) * 4);
  int*   cursor  = (int*)  carve((size_t)NODES0 * 4);
  float* dis     = (float*)carve((size_t)NODES0 * 4);
  float* score   = (float*)carve((size_t)NODES0 * 4);
  int*   cur_map = (int*)  carve((size_t)NODES0 * 4);
  int*   cum_map = (int*)  carve((size_t)NODES0 * 4);
  int*   perm    = (int*)  carve((size_t)NODES0 * 4);
  float* gate    = (float*)carve((size_t)NODES0 * 4);
  int*   bsum    = (int*)  carve(256 * 4);
  float* pinv    = (float*)carve(16);
  _Float16* Wimg = (_Float16*)carve((size_t)2 * 8 * 128 * TSTRIDE * 2);  // 288 KB
  (void)ws_size; (void)in_sizes; (void)n_in; (void)out_size;

  pnorm_kernel<<<3, 256, 0, stream>>>(pl[0], pl[1], pl[2], pinv);
  init_cum_kernel<<<NODES0 / 256, 256, 0, stream>>>(cum_map, NODES0);

  int n_cur = N0_;
  const float* xin = x;
  for (int l = 0; l < 3; ++l) {
    int nodes = G_ * n_cur;
    float* hlin = (l & 1) ? bufB : bufA;
    float* hbuf = (l & 1) ? bufA : bufB;
    float* xnew = hlin;

    // h_lin = X @ W  via f16x3 MFMA
    wconv_kernel<<<16, 256, 0, stream>>>(Wl[l], Wimg);
    gemm_f16x3_kernel<<<(nodes / 128) * 2, 256, 0, stream>>>(xin, Wimg, hlin);

    hipMemsetAsync(cnt, 0, (size_t)nodes * 4, stream);
    count_deg_kernel<<<E_ / 256, 256, 0, stream>>>(esrc, edst, cum_map, cnt);
    int nb = (nodes + 1023) / 1024;
    scan1_kernel<<<nb, 256, 0, stream>>>(cnt, row_st, bsum, dis, nodes);
    scan2_kernel<<<1, 256, 0, stream>>>(bsum, row_st, nb, nodes);
    scan3_kernel<<<(nodes + 255) / 256, 256, 0, stream>>>(row_st, bsum, nodes);
    hipMemsetAsync(cursor, 0, (size_t)nodes * 4, stream);
    fill_csr_kernel<<<E_ / 256, 256, 0, stream>>>(esrc, edst, cum_map, row_st, cursor, dis,
                                                  csr_src, csr_cf);

    int agg_blocks = nodes / 4;
    agg_score_kernel<<<agg_blocks, 256, 0, stream>>>(
        (const float4*)hlin, dis, (const float4*)bl[l], row_st, csr_src, csr_cf,
        (const float4*)pl[l], pinv + l, (float4*)hbuf, score, agg_blocks / 8);

    int kk = (int)std::ceil(0.8 * (double)n_cur);
    topk_kernel<<<G_, 256, 0, stream>>>(score, n_cur, kk, cur_map, perm);
    update_cum_kernel<<<NODES0 / 256, 256, 0, stream>>>(cum_map, cur_map, NODES0);
    int rows = G_ * kk;
    int gg_blocks = rows / 4;
    gather_gate_kernel<<<gg_blocks, 256, 0, stream>>>(
        (const float4*)hbuf, score, perm, (const float4*)attw, attb,
        (float4*)xnew, gate, gg_blocks / 8);

    att_pool_kernel<<<G_, 512, 0, stream>>>((const float4*)xnew, gate, out, kk, l > 0 ? 1 : 0);

    n_cur = kk;
    xin = xnew;
  }
}